// Round 3
// baseline (206.764 us; speedup 1.0000x reference)
//
#include <hip/hip_runtime.h>
#include <cstdint>

#define NROWS 262144
#define DDIM 64
#define KCL 512
#define BM 32
#define THREADS 256

typedef __attribute__((ext_vector_type(8))) short short8;
typedef __attribute__((ext_vector_type(16))) float f32x16;

__device__ __forceinline__ unsigned short bf16_rne(float f) {
  unsigned u = __builtin_bit_cast(unsigned, f);
  unsigned r = (u + 0x7FFFu + ((u >> 16) & 1u)) >> 16;
  return (unsigned short)r;
}
__device__ __forceinline__ float bf16_to_f(unsigned short h) {
  unsigned u = ((unsigned)h) << 16;
  return __builtin_bit_cast(float, u);
}

// Pack centroids into MFMA-fragment order + compute ||c||^2.
// Fragment layout: byte addr = (T*4+kk)*2048 + l*16 for hi, +1024 for lo.
// Element: lane l holds B[col=T*32+(l&31)][d = kk*16 + (l>>5)*8 + i], i=0..7.
__global__ void prep_kernel(const float* __restrict__ c,
                            char* __restrict__ bpack,
                            float* __restrict__ csq) {
  __shared__ float sS[256];
  const int T = blockIdx.x;       // 0..15
  const int tid = threadIdx.x;    // 0..255
  const int kk = tid >> 6, l = tid & 63;
  const int col = T * 32 + (l & 31);
  const int d0 = kk * 16 + (l >> 5) * 8;
  const float* cp = c + col * DDIM + d0;
  float4 v0 = *(const float4*)cp;
  float4 v1 = *(const float4*)(cp + 4);
  float xv[8] = {v0.x, v0.y, v0.z, v0.w, v1.x, v1.y, v1.z, v1.w};
  short8 hh, ll;
  float s = 0.f;
#pragma unroll
  for (int i = 0; i < 8; ++i) {
    unsigned short h = bf16_rne(xv[i]);
    hh[i] = (short)h;
    ll[i] = (short)bf16_rne(xv[i] - bf16_to_f(h));
    s = fmaf(xv[i], xv[i], s);
  }
  char* dst = bpack + (T * 4 + kk) * 2048 + l * 16;
  *(short8*)dst = hh;
  *(short8*)(dst + 1024) = ll;
  sS[tid] = s;
  __syncthreads();
  if (tid < 32) {
    float t = 0.f;
#pragma unroll
    for (int k2 = 0; k2 < 4; ++k2)
#pragma unroll
      for (int h2 = 0; h2 < 2; ++h2) t += sS[k2 * 64 + h2 * 32 + tid];
    csq[T * 32 + tid] = t;
  }
}

__global__ __launch_bounds__(THREADS) void cluster_kernel(
    const float* __restrict__ xg,
    const char* __restrict__ bpack,   // fragment-packed bf16 hi/lo, 128 KB
    const float* __restrict__ csq,
    float* __restrict__ outg) {
  __shared__ __align__(16) char sXh[4096];  // 32x64 bf16 hi, XOR-swizzled
  __shared__ __align__(16) char sXl[4096];
  __shared__ float sX1[BM];                 // 1 + ||x_r||^2
  __shared__ __align__(16) float sPart[BM][4];

  const int tid = threadIdx.x;
  const int lane = tid & 63;
  const int wv = tid >> 6;
  const int half = lane >> 5;
  const int l5 = lane & 31;
  const long rowBase = (long)blockIdx.x * BM;

  // ---- load X tile, split to bf16 hi/lo, write LDS swizzled ----
  {
    int r = tid >> 3, d0 = (tid & 7) * 8;
    const float* xp = xg + (rowBase + r) * DDIM + d0;
    float4 v0 = *(const float4*)xp;
    float4 v1 = *(const float4*)(xp + 4);
    float xv[8] = {v0.x, v0.y, v0.z, v0.w, v1.x, v1.y, v1.z, v1.w};
    short8 hh, ll;
    float s = 0.f;
#pragma unroll
    for (int i = 0; i < 8; ++i) {
      unsigned short h = bf16_rne(xv[i]);
      hh[i] = (short)h;
      ll[i] = (short)bf16_rne(xv[i] - bf16_to_f(h));
      s = fmaf(xv[i], xv[i], s);
    }
    int byte = (r * 128 + d0 * 2) ^ ((r & 7) << 4);
    *(short8*)(sXh + byte) = hh;
    *(short8*)(sXl + byte) = ll;
    s += __shfl_xor(s, 1, 64);
    s += __shfl_xor(s, 2, 64);
    s += __shfl_xor(s, 4, 64);
    if ((tid & 7) == 0) sX1[r] = 1.f + s;
  }

  __syncthreads();  // X tile visible

  // ---- A fragments: lane l -> row l&31, d = kk*16 + half*8 ----
  short8 ah[4], al[4];
#pragma unroll
  for (int kk = 0; kk < 4; ++kk) {
    int byte = (l5 * 128 + kk * 32 + half * 16) ^ ((l5 & 7) << 4);
    ah[kk] = *(const short8*)(sXh + byte);
    al[kk] = *(const short8*)(sXl + byte);
  }

  // ---- ||c||^2 for this thread's 4 tiles ----
  float c1[4];
#pragma unroll
  for (int t = 0; t < 4; ++t)
    c1[t] = csq[((t >> 1) * 8 + wv + 4 * (t & 1)) * 32 + l5];

  // ---- 1 + ||x||^2 per (reg, half) ----
  float x1v[16];
#pragma unroll
  for (int r = 0; r < 16; ++r)
    x1v[r] = sX1[(r & 3) + 8 * (r >> 2) + 4 * half];

  f32x16 acc[4];
#pragma unroll
  for (int i = 0; i < 4; ++i)
#pragma unroll
    for (int j = 0; j < 16; ++j) acc[i][j] = 0.f;

  // ---- MFMA over coalesced fragment-packed B (L2-resident) ----
#pragma unroll
  for (int t = 0; t < 4; ++t) {
    const int T = (t >> 1) * 8 + wv + 4 * (t & 1);
    const char* fb = bpack + T * 8192 + lane * 16;
#pragma unroll
    for (int kk = 0; kk < 4; ++kk) {
      short8 bh = *(const short8*)(fb + kk * 2048);
      short8 bl = *(const short8*)(fb + kk * 2048 + 1024);
      acc[t] = __builtin_amdgcn_mfma_f32_32x32x16_bf16(ah[kk], bh, acc[t], 0, 0, 0);
      acc[t] = __builtin_amdgcn_mfma_f32_32x32x16_bf16(al[kk], bh, acc[t], 0, 0, 0);
      acc[t] = __builtin_amdgcn_mfma_f32_32x32x16_bf16(ah[kk], bl, acc[t], 0, 0, 0);
    }
  }

  // ---- q = 1/(1+dist2) in place ----
#pragma unroll
  for (int t = 0; t < 4; ++t)
#pragma unroll
    for (int r = 0; r < 16; ++r) {
      float tv = fmaf(-2.f, acc[t][r], x1v[r] + c1[t]);
      acc[t][r] = __builtin_amdgcn_rcpf(tv);
    }

  // ---- row sums: tiles -> lanes -> cross-wave via LDS ----
  float rs[16];
#pragma unroll
  for (int r = 0; r < 16; ++r) {
    float s = (acc[0][r] + acc[1][r]) + (acc[2][r] + acc[3][r]);
    s += __shfl_xor(s, 1, 64);
    s += __shfl_xor(s, 2, 64);
    s += __shfl_xor(s, 4, 64);
    s += __shfl_xor(s, 8, 64);
    s += __shfl_xor(s, 16, 64);
    rs[r] = s;
  }
#pragma unroll
  for (int r = 0; r < 16; ++r) {
    if (l5 == r) sPart[(r & 3) + 8 * (r >> 2) + 4 * half][wv] = rs[r];
  }
  __syncthreads();

  // ---- scale + store ----
#pragma unroll
  for (int r = 0; r < 16; ++r) {
    int row = (r & 3) + 8 * (r >> 2) + 4 * half;
    float4 p = *(const float4*)&sPart[row][0];
    float inv = __builtin_amdgcn_rcpf((p.x + p.y) + (p.z + p.w));
    float* op = outg + (rowBase + row) * (long)KCL + l5;
#pragma unroll
    for (int t = 0; t < 4; ++t) {
      int tile = (t >> 1) * 8 + wv + 4 * (t & 1);
      op[tile * 32] = acc[t][r] * inv;
    }
  }
}

extern "C" void kernel_launch(void* const* d_in, const int* in_sizes, int n_in,
                              void* d_out, int out_size, void* d_ws, size_t ws_size,
                              hipStream_t stream) {
  const float* x = (const float*)d_in[0];
  const float* c = (const float*)d_in[1];
  float* out = (float*)d_out;

  char* bpack = (char*)d_ws;                          // 128 KB fragment-packed
  float* csq = (float*)((char*)d_ws + 131072);        // 2 KB

  hipLaunchKernelGGL(prep_kernel, dim3(16), dim3(256), 0, stream, c, bpack, csq);
  hipLaunchKernelGGL(cluster_kernel, dim3(NROWS / BM), dim3(THREADS), 0, stream,
                     x, bpack, csq, out);
}

// Round 4
// 152.718 us; speedup vs baseline: 1.3539x; 1.3539x over previous
//
#include <hip/hip_runtime.h>
#include <cstdint>

#define NROWS 262144
#define DDIM 64
#define KCL 512
#define BM 32
#define THREADS 256

typedef __attribute__((ext_vector_type(8))) _Float16 half8;
typedef __attribute__((ext_vector_type(16))) float f32x16;
typedef const __attribute__((address_space(1))) void* gas_ptr;
typedef __attribute__((address_space(3))) void* las_ptr;

__device__ __forceinline__ void g2lds16(const void* g, void* l) {
  // async global->LDS, 16B/lane; LDS dest = wave-uniform base + lane*16
  __builtin_amdgcn_global_load_lds((gas_ptr)g, (las_ptr)l, 16, 0, 0);
}

// Pack centroids to fp16 (RNE) MFMA fragments, chunk-major, + ||c||^2.
// byte addr = T*4096 + kk*1024 + lane*16 ; lane l holds
// C[col = T*32 + (l&31)][d = kk*16 + (l>>5)*8 + i], i = 0..7.
__global__ void prep_kernel(const float* __restrict__ c,
                            char* __restrict__ bpack,
                            float* __restrict__ csq) {
  __shared__ float sS[256];
  const int T = blockIdx.x;     // tile 0..15
  const int tid = threadIdx.x;  // 0..255
  const int kk = tid >> 6, l = tid & 63;
  const int col = T * 32 + (l & 31);
  const int d0 = kk * 16 + ((l >> 5) << 3);
  const float* cp = c + col * DDIM + d0;
  float4 v0 = *(const float4*)cp;
  float4 v1 = *(const float4*)(cp + 4);
  float xv[8] = {v0.x, v0.y, v0.z, v0.w, v1.x, v1.y, v1.z, v1.w};
  half8 hh;
  float s = 0.f;
#pragma unroll
  for (int i = 0; i < 8; ++i) {
    hh[i] = (_Float16)xv[i];  // RNE
    s = fmaf(xv[i], xv[i], s);
  }
  *(half8*)(bpack + T * 4096 + kk * 1024 + l * 16) = hh;
  sS[tid] = s;
  __syncthreads();
  if (tid < 32) {
    float t = 0.f;
#pragma unroll
    for (int k2 = 0; k2 < 4; ++k2)
#pragma unroll
      for (int h2 = 0; h2 < 2; ++h2) t += sS[k2 * 64 + h2 * 32 + tid];
    csq[T * 32 + tid] = t;
  }
}

__global__ __launch_bounds__(THREADS, 4) void cluster_kernel(
    const float* __restrict__ xg,
    const char* __restrict__ bpack,   // fp16 fragment-packed, 64 KB
    const float* __restrict__ csq,
    float* __restrict__ outg) {
  __shared__ __align__(16) char sB[2][16384];  // 128-col fp16 chunk, dbuf
  __shared__ float sX1[BM];                    // 1 + ||x_r||^2
  __shared__ __align__(16) float sPart[BM][4];

  const int tid = threadIdx.x;
  const int lane = tid & 63;
  const int wv = tid >> 6;
  const int half = lane >> 5;
  const int l5 = lane & 31;
  const long rowBase = (long)blockIdx.x * BM;

  // ---- issue stage of chunk 0 -> sB[0] (16 KB, linear) ----
#pragma unroll
  for (int i = 0; i < 4; ++i) {
    int p = (i * THREADS + tid) * 16;
    g2lds16(bpack + p, (char*)sB[0] + p);
  }

  // ---- ||c||^2 for this thread's 4 tiles (tile = ch*4 + wv) ----
  float c1[4];
#pragma unroll
  for (int t = 0; t < 4; ++t) c1[t] = csq[(t * 4 + wv) * 32 + l5];

  // ---- X fragments straight from global: lane -> row l&31, d = kk*16+half*8 ----
  half8 xh[4], xl[4];
  {
    const float* xrow = xg + (rowBase + l5) * DDIM + half * 8;
#pragma unroll
    for (int kk = 0; kk < 4; ++kk) {
      float4 a = *(const float4*)(xrow + kk * 16);
      float4 b = *(const float4*)(xrow + kk * 16 + 4);
      float v[8] = {a.x, a.y, a.z, a.w, b.x, b.y, b.z, b.w};
#pragma unroll
      for (int i = 0; i < 8; ++i) {
        _Float16 h = (_Float16)v[i];
        xh[kk][i] = h;
        xl[kk][i] = (_Float16)(v[i] - (float)h);
      }
    }
  }

  // ---- 1 + ||x_r||^2 (threads 0..31, rows L1-hot) ----
  if (tid < BM) {
    const float4* xr = (const float4*)(xg + (rowBase + tid) * DDIM);
    float s = 1.f;
#pragma unroll
    for (int i = 0; i < DDIM / 4; ++i) {
      float4 v = xr[i];
      s = fmaf(v.x, v.x, s);
      s = fmaf(v.y, v.y, s);
      s = fmaf(v.z, v.z, s);
      s = fmaf(v.w, v.w, s);
    }
    sX1[tid] = s;
  }

  __syncthreads();  // chunk0 staged (vmcnt drained) + sX1 visible

  f32x16 acc[4];
#pragma unroll
  for (int t = 0; t < 4; ++t)
#pragma unroll
    for (int j = 0; j < 16; ++j) acc[t][j] = 0.f;

  // ---- 4 chunks x (stage next | 8 MFMA | q-transform) ----
#pragma unroll
  for (int ch = 0; ch < 4; ++ch) {
    if (ch < 3) {
#pragma unroll
      for (int i = 0; i < 4; ++i) {
        int p = (i * THREADS + tid) * 16;
        g2lds16(bpack + (ch + 1) * 16384 + p, (char*)sB[(ch + 1) & 1] + p);
      }
    }
    const char* fb = (const char*)sB[ch & 1] + wv * 4096 + lane * 16;
#pragma unroll
    for (int kk = 0; kk < 4; ++kk) {
      half8 bh = *(const half8*)(fb + kk * 1024);
      acc[ch] = __builtin_amdgcn_mfma_f32_32x32x16_f16(xh[kk], bh, acc[ch], 0, 0, 0);
      acc[ch] = __builtin_amdgcn_mfma_f32_32x32x16_f16(xl[kk], bh, acc[ch], 0, 0, 0);
    }
    // q = 1/(1+dist2) for this chunk (overlaps next stage's latency)
#pragma unroll
    for (int r = 0; r < 16; ++r) {
      float x1r = sX1[(r & 3) + 8 * (r >> 2) + 4 * half];
      float tv = fmaf(-2.f, acc[ch][r], x1r + c1[ch]);
      acc[ch][r] = __builtin_amdgcn_rcpf(tv);
    }
    if (ch < 3) __syncthreads();  // next chunk staged; prev buffer free
  }

  // ---- row sums: tiles -> lanes -> cross-wave via LDS ----
  float rs[16];
#pragma unroll
  for (int r = 0; r < 16; ++r) {
    float s = (acc[0][r] + acc[1][r]) + (acc[2][r] + acc[3][r]);
    s += __shfl_xor(s, 1, 64);
    s += __shfl_xor(s, 2, 64);
    s += __shfl_xor(s, 4, 64);
    s += __shfl_xor(s, 8, 64);
    s += __shfl_xor(s, 16, 64);
    rs[r] = s;
  }
#pragma unroll
  for (int r = 0; r < 16; ++r) {
    if (l5 == r) sPart[(r & 3) + 8 * (r >> 2) + 4 * half][wv] = rs[r];
  }
  __syncthreads();

  // ---- scale + store (two 128B segments per store inst) ----
#pragma unroll
  for (int r = 0; r < 16; ++r) {
    int row = (r & 3) + 8 * (r >> 2) + 4 * half;
    float4 p = *(const float4*)&sPart[row][0];
    float inv = __builtin_amdgcn_rcpf((p.x + p.y) + (p.z + p.w));
    float* op = outg + (rowBase + row) * (long)KCL + l5;
#pragma unroll
    for (int t = 0; t < 4; ++t) op[(t * 4 + wv) * 32] = acc[t][r] * inv;
  }
}

extern "C" void kernel_launch(void* const* d_in, const int* in_sizes, int n_in,
                              void* d_out, int out_size, void* d_ws, size_t ws_size,
                              hipStream_t stream) {
  const float* x = (const float*)d_in[0];
  const float* c = (const float*)d_in[1];
  float* out = (float*)d_out;

  char* bpack = (char*)d_ws;                    // 64 KB fp16 fragments
  float* csq = (float*)((char*)d_ws + 65536);   // 2 KB

  hipLaunchKernelGGL(prep_kernel, dim3(16), dim3(256), 0, stream, c, bpack, csq);
  hipLaunchKernelGGL(cluster_kernel, dim3(NROWS / BM), dim3(THREADS), 0, stream,
                     x, bpack, csq, out);
}